// Round 5
// baseline (6867.269 us; speedup 1.0000x reference)
//
#include <hip/hip_runtime.h>

#define BB    64
#define TT    512
#define INP   256
#define HID   1024
#define OUTP  256
#define G4    4096
#define KK    1280   // HID + INP
#define NGATE 64
#define NOUT  8
#define NB    72     // 64 gate blocks + 8 out blocks
#define FSTR  16     // dwords per flag line (gather-probe only)
#define PITER 128    // probe barrier iterations

typedef _Float16 half_t;
typedef __attribute__((ext_vector_type(8))) _Float16 half8;
typedef __attribute__((ext_vector_type(4))) float f32x4;
typedef unsigned long long ull;

union U16 { ull u[2]; half8 v; };

__device__ __forceinline__ float sigf(float x) { return 1.0f / (1.0f + __expf(-x)); }
// MALL-coherent (L1+L2 bypass) accessors — no fences needed anywhere.
__device__ __forceinline__ ull ald(const ull* p) {
  return __hip_atomic_load(p, __ATOMIC_RELAXED, __HIP_MEMORY_SCOPE_AGENT);
}
__device__ __forceinline__ void ast(ull* p, ull v) {
  __hip_atomic_store(p, v, __ATOMIC_RELAXED, __HIP_MEMORY_SCOPE_AGENT);
}
__device__ __forceinline__ unsigned aldu(const unsigned* p) {
  return __hip_atomic_load(p, __ATOMIC_RELAXED, __HIP_MEMORY_SCOPE_AGENT);
}
__device__ __forceinline__ void astu(unsigned* p, unsigned v) {
  __hip_atomic_store(p, v, __ATOMIC_RELAXED, __HIP_MEMORY_SCOPE_AGENT);
}

// ---------------- setup: convert weights/x to fp16, zero all flag regions ----------------
__global__ void setup_kernel(const float* __restrict__ x, const float* __restrict__ W_ih,
                             const float* __restrict__ W_hh, const float* __restrict__ b_ih,
                             const float* __restrict__ b_hh, const float* __restrict__ W_out,
                             half_t* __restrict__ Wp, half_t* __restrict__ Wo,
                             half_t* __restrict__ x16, float* __restrict__ bsum,
                             unsigned* __restrict__ fzero, int nflags) {
  const int stride = gridDim.x * blockDim.x;
  const int i0 = blockIdx.x * blockDim.x + threadIdx.x;
  for (int i = i0; i < nflags; i += stride) fzero[i] = 0u;
  for (int i = i0; i < G4 * KK; i += stride) {
    int n = i / KK, k = i - n * KK;
    float v = (k < HID) ? W_hh[n * HID + k] : W_ih[n * INP + (k - HID)];
    Wp[i] = (half_t)v;
  }
  for (int i = i0; i < OUTP * HID; i += stride) Wo[i] = (half_t)W_out[i];
  for (int i = i0; i < BB * TT * INP; i += stride) x16[i] = (half_t)x[i];
  for (int i = i0; i < G4; i += stride) bsum[i] = b_ih[i] + b_hh[i];
}

// ================= DIAGNOSTIC PROBES (do not touch d_out) =================
// Probe A: R4-style barrier — 64-line gather poll (64B-padded flags)
__global__ __launch_bounds__(256, 1) void probe_gather(unsigned* __restrict__ fl) {
  const int tid = threadIdx.x, lane = tid & 63;
  for (int ph = 1; ph <= PITER; ++ph) {
    __syncthreads();
    if (tid == 0) astu(&fl[blockIdx.x * FSTR], (unsigned)ph);
    if (tid < 64) {
      for (;;) {
        unsigned v0 = aldu(&fl[lane * FSTR]);
        unsigned v1 = (lane < NOUT) ? aldu(&fl[(64 + lane) * FSTR]) : 0xFFFFFFFFu;
        if (__all(v0 >= (unsigned)ph && v1 >= (unsigned)ph)) break;
        __builtin_amdgcn_s_sleep(1);
      }
    }
    __syncthreads();
  }
}
// Probe B: compact flags — 72 consecutive dwords, poll = 2 coalesced loads
__global__ __launch_bounds__(256, 1) void probe_compact(unsigned* __restrict__ fl) {
  const int tid = threadIdx.x, lane = tid & 63;
  for (int ph = 1; ph <= PITER; ++ph) {
    __syncthreads();
    if (tid == 0) astu(&fl[blockIdx.x], (unsigned)ph);
    if (tid < 64) {
      for (;;) {
        unsigned v0 = aldu(&fl[lane]);
        unsigned v1 = (lane < NOUT) ? aldu(&fl[64 + lane]) : 0xFFFFFFFFu;
        if (__all(v0 >= (unsigned)ph && v1 >= (unsigned)ph)) break;
        __builtin_amdgcn_s_sleep(1);
      }
    }
    __syncthreads();
  }
}
// Probe C: two-level epoch — block0 aggregates compact flags, others poll one word
__global__ __launch_bounds__(256, 1) void probe_epoch(unsigned* __restrict__ fl,
                                                      unsigned* __restrict__ ep) {
  const int tid = threadIdx.x, lane = tid & 63;
  for (int ph = 1; ph <= PITER; ++ph) {
    __syncthreads();
    if (blockIdx.x == 0) {
      if (tid == 0) astu(&fl[0], (unsigned)ph);
      if (tid < 64) {
        for (;;) {
          unsigned v0 = aldu(&fl[lane]);
          unsigned v1 = (lane < NOUT) ? aldu(&fl[64 + lane]) : 0xFFFFFFFFu;
          if (__all(v0 >= (unsigned)ph && v1 >= (unsigned)ph)) break;
          __builtin_amdgcn_s_sleep(1);
        }
      }
      __syncthreads();
      if (tid == 0) astu(&ep[0], (unsigned)ph);
    } else {
      if (tid == 0) astu(&fl[blockIdx.x], (unsigned)ph);
      if (tid < 64) {
        while (aldu(&ep[0]) < (unsigned)ph) __builtin_amdgcn_s_sleep(1);
      }
      __syncthreads();
    }
  }
}

// ---------------- fence-free flag barrier (compact flags) ----------------
__device__ __forceinline__ void bar_arrive(unsigned* __restrict__ flags, unsigned ph) {
  __syncthreads();  // all waves' h-stores (vmcnt) drained before the flag goes out
  if (threadIdx.x == 0) astu(&flags[blockIdx.x], ph);
}
__device__ __forceinline__ void bar_wait(unsigned* __restrict__ flags, unsigned target) {
  if ((threadIdx.x >> 6) == 0) {   // wave 0 polls; others park at the barrier
    const int lane = threadIdx.x & 63;
    for (;;) {
      unsigned v0 = aldu(&flags[lane]);
      unsigned v1 = (lane < NOUT) ? aldu(&flags[64 + lane]) : 0xFFFFFFFFu;
      if (__all(v0 >= target && v1 >= target)) break;
      __builtin_amdgcn_s_sleep(1);
    }
  }
  __syncthreads();
}

// ---------------- persistent LSTM (identical to R4 except compact flags) ----------------
__global__ __launch_bounds__(256, 1) void lstm_persist(
    const half_t* __restrict__ Wp,   // (4096, 1280)
    const half_t* __restrict__ Wo,   // (256, 1024)
    const half_t* __restrict__ x16,  // (64, 512, 256)
    const float* __restrict__ bsum,  // (4096)
    const float* __restrict__ b_out, // (256)
    half_t* __restrict__ hbuf,       // 2 x (64, 1024), h_p in slot p&1 (MALL-only data)
    float* __restrict__ out,         // (64, 512, 256)
    unsigned* __restrict__ flags)
{
  __shared__ float Pf[4 * 64 * 68];  // 69.6 KB partials (row stride 68 dwords)
  __shared__ float biasg[64];
  f32x4* P4 = (f32x4*)Pf;
  const int tid  = threadIdx.x;
  const int wave = tid >> 6;
  const int lane = tid & 63;
  const int l15  = lane & 15;
  const int lhi  = lane >> 4;

  if (blockIdx.x < NGATE) {
    // ================= gate block =================
    const int u0 = blockIdx.x * 16;
    if (tid < 64) biasg[tid] = bsum[(tid & 3) * HID + u0 + (tid >> 2)];  // [uu][g]
    half8 b[10][4];
    #pragma unroll
    for (int jj = 0; jj < 10; ++jj) {
      const int c = wave + 4 * jj;
      #pragma unroll
      for (int g = 0; g < 4; ++g) {
        const int r = g * HID + u0 + l15;
        b[jj][g] = *(const half8*)&Wp[(size_t)r * KK + 32 * c + 8 * lhi];
      }
    }
    __syncthreads();
    const int rrow = tid >> 2;       // reducer: row 0..63
    const int ug   = (tid & 3) * 4;  // units ug..ug+3
    float cst[4] = {0.f, 0.f, 0.f, 0.f};

    for (int ph = 1; ph <= TT; ++ph) {
      const int t = ph - 1;
      f32x4 acc[4][4];
      #pragma unroll
      for (int m = 0; m < 4; ++m)
        #pragma unroll
        for (int g = 0; g < 4; ++g) acc[m][g] = (f32x4){0.f, 0.f, 0.f, 0.f};
      #pragma unroll
      for (int jx = 0; jx < 2; ++jx) {
        const int kx = 32 * (wave + 4 * jx) + 8 * lhi;
        #pragma unroll
        for (int m = 0; m < 4; ++m) {
          half8 a = *(const half8*)&x16[((size_t)(16 * m + l15) * TT + t) * INP + kx];
          #pragma unroll
          for (int g = 0; g < 4; ++g)
            acc[m][g] = __builtin_amdgcn_mfma_f32_16x16x32_f16(a, b[8 + jx][g], acc[m][g], 0, 0, 0);
        }
      }
      if (ph > 1) {
        bar_wait(flags, (unsigned)(ph - 1));
        const half_t* __restrict__ hcur = hbuf + (size_t)((ph - 1) & 1) * (BB * HID);
        U16 ahA[4][4], ahB[4][4];
        #pragma unroll
        for (int jj = 0; jj < 4; ++jj) {
          const int k0 = 32 * (wave + 4 * jj) + 8 * lhi;
          #pragma unroll
          for (int m = 0; m < 4; ++m) {
            const ull* p = (const ull*)&hcur[(size_t)(16 * m + l15) * HID + k0];
            ahA[jj][m].u[0] = ald(p);
            ahA[jj][m].u[1] = ald(p + 1);
          }
        }
        #pragma unroll
        for (int jj = 4; jj < 8; ++jj) {
          const int k0 = 32 * (wave + 4 * jj) + 8 * lhi;
          #pragma unroll
          for (int m = 0; m < 4; ++m) {
            const ull* p = (const ull*)&hcur[(size_t)(16 * m + l15) * HID + k0];
            ahB[jj - 4][m].u[0] = ald(p);
            ahB[jj - 4][m].u[1] = ald(p + 1);
          }
        }
        #pragma unroll
        for (int jj = 0; jj < 4; ++jj)
          #pragma unroll
          for (int m = 0; m < 4; ++m)
            #pragma unroll
            for (int g = 0; g < 4; ++g)
              acc[m][g] = __builtin_amdgcn_mfma_f32_16x16x32_f16(ahA[jj][m].v, b[jj][g], acc[m][g], 0, 0, 0);
        #pragma unroll
        for (int jj = 4; jj < 8; ++jj)
          #pragma unroll
          for (int m = 0; m < 4; ++m)
            #pragma unroll
            for (int g = 0; g < 4; ++g)
              acc[m][g] = __builtin_amdgcn_mfma_f32_16x16x32_f16(ahB[jj - 4][m].v, b[jj][g], acc[m][g], 0, 0, 0);
      }
      #pragma unroll
      for (int m = 0; m < 4; ++m)
        #pragma unroll
        for (int g = 0; g < 4; ++g)
          #pragma unroll
          for (int r = 0; r < 4; ++r) {
            const int row  = 16 * m + 4 * lhi + r;
            const int slot = (l15 + row) & 15;
            Pf[(wave * 64 + row) * 68 + slot * 4 + g] = acc[m][g][r];
          }
      __syncthreads();
      half_t* __restrict__ hnext = hbuf + (size_t)(ph & 1) * (BB * HID);
      {
        half_t hv[4];
        #pragma unroll
        for (int uu = 0; uu < 4; ++uu) {
          const int u    = ug + uu;
          const int slot = (u + rrow) & 15;
          f32x4 s = *(const f32x4*)&Pf[(0 * 64 + rrow) * 68 + slot * 4];
          #pragma unroll
          for (int w = 1; w < 4; ++w) s += *(const f32x4*)&Pf[(w * 64 + rrow) * 68 + slot * 4];
          f32x4 bb = *(const f32x4*)&biasg[4 * u];
          float iv = sigf(s[0] + bb[0]);
          float fv = sigf(s[1] + bb[1]);
          float gv = tanhf(s[2] + bb[2]);
          float ov = sigf(s[3] + bb[3]);
          cst[uu] = fv * cst[uu] + iv * gv;
          hv[uu]  = (half_t)(ov * tanhf(cst[uu]));
        }
        union { ull u64; half_t h[4]; } pk;
        pk.h[0] = hv[0]; pk.h[1] = hv[1]; pk.h[2] = hv[2]; pk.h[3] = hv[3];
        ast((ull*)&hnext[(size_t)rrow * HID + u0 + ug], pk.u64);
      }
      bar_arrive(flags, (unsigned)ph);
    }
  } else {
    // ================= out block =================
    const int ob    = blockIdx.x - NGATE;
    const int obase = ob * 32;
    if (tid < 32) biasg[tid] = b_out[obase + tid];
    half8 b[8][2];
    #pragma unroll
    for (int j = 0; j < 8; ++j) {
      const int c = wave + 4 * j;
      #pragma unroll
      for (int n = 0; n < 2; ++n) {
        const int col = obase + 16 * n + l15;
        b[j][n] = *(const half8*)&Wo[(size_t)col * HID + 32 * c + 8 * lhi];
      }
    }
    __syncthreads();
    bar_arrive(flags, 1u);
    const int rrow = tid >> 2;
    const int cg0  = 2 * (tid & 3);
    for (int ph = 2; ph <= TT + 1; ++ph) {
      bar_wait(flags, (unsigned)(ph - 1));
      const half_t* __restrict__ hcur = hbuf + (size_t)((ph - 1) & 1) * (BB * HID);
      U16 ahA[4][4], ahB[4][4];
      #pragma unroll
      for (int j = 0; j < 4; ++j) {
        const int k0 = 32 * (wave + 4 * j) + 8 * lhi;
        #pragma unroll
        for (int m = 0; m < 4; ++m) {
          const ull* p = (const ull*)&hcur[(size_t)(16 * m + l15) * HID + k0];
          ahA[j][m].u[0] = ald(p);
          ahA[j][m].u[1] = ald(p + 1);
        }
      }
      #pragma unroll
      for (int j = 4; j < 8; ++j) {
        const int k0 = 32 * (wave + 4 * j) + 8 * lhi;
        #pragma unroll
        for (int m = 0; m < 4; ++m) {
          const ull* p = (const ull*)&hcur[(size_t)(16 * m + l15) * HID + k0];
          ahB[j - 4][m].u[0] = ald(p);
          ahB[j - 4][m].u[1] = ald(p + 1);
        }
      }
      f32x4 acc[4][2];
      #pragma unroll
      for (int m = 0; m < 4; ++m)
        #pragma unroll
        for (int n = 0; n < 2; ++n) acc[m][n] = (f32x4){0.f, 0.f, 0.f, 0.f};
      #pragma unroll
      for (int j = 0; j < 4; ++j)
        #pragma unroll
        for (int m = 0; m < 4; ++m)
          #pragma unroll
          for (int n = 0; n < 2; ++n)
            acc[m][n] = __builtin_amdgcn_mfma_f32_16x16x32_f16(ahA[j][m].v, b[j][n], acc[m][n], 0, 0, 0);
      #pragma unroll
      for (int j = 4; j < 8; ++j)
        #pragma unroll
        for (int m = 0; m < 4; ++m)
          #pragma unroll
          for (int n = 0; n < 2; ++n)
            acc[m][n] = __builtin_amdgcn_mfma_f32_16x16x32_f16(ahB[j - 4][m].v, b[j][n], acc[m][n], 0, 0, 0);
      #pragma unroll
      for (int m = 0; m < 4; ++m)
        #pragma unroll
        for (int n = 0; n < 2; ++n)
          #pragma unroll
          for (int r = 0; r < 4; ++r) {
            const int row  = 16 * m + 4 * lhi + r;
            const int col  = 16 * n + l15;
            const int cs   = col >> 2, off = col & 3;
            const int scol = (((cs + row) & 7) << 2) + off;
            Pf[(wave * 64 + row) * 32 + scol] = acc[m][n][r];
          }
      __syncthreads();
      const int tm1 = ph - 2;
      #pragma unroll
      for (int uu = 0; uu < 2; ++uu) {
        const int cg  = cg0 + uu;
        const int scg = (cg + rrow) & 7;
        f32x4 s = P4[(0 * 64 + rrow) * 8 + scg];
        #pragma unroll
        for (int w = 1; w < 4; ++w) s += P4[(w * 64 + rrow) * 8 + scg];
        f32x4 bb = *(const f32x4*)&biasg[4 * cg];
        f32x4 o  = s + bb;
        *(f32x4*)&out[((size_t)rrow * TT + tm1) * OUTP + obase + 4 * cg] = o;
      }
      if (ph <= TT) bar_arrive(flags, (unsigned)ph);
      else __syncthreads();
    }
  }
}

extern "C" void kernel_launch(void* const* d_in, const int* in_sizes, int n_in,
                              void* d_out, int out_size, void* d_ws, size_t ws_size,
                              hipStream_t stream) {
  const float* x     = (const float*)d_in[0];
  const float* W_ih  = (const float*)d_in[1];
  const float* W_hh  = (const float*)d_in[2];
  const float* b_ih  = (const float*)d_in[3];
  const float* b_hh  = (const float*)d_in[4];
  const float* W_out = (const float*)d_in[5];
  const float* b_out = (const float*)d_in[6];
  float* out = (float*)d_out;

  char* ws = (char*)d_ws;
  size_t off = 0;
  half_t* Wp  = (half_t*)(ws + off); off += (size_t)G4 * KK * sizeof(half_t);
  half_t* Wo  = (half_t*)(ws + off); off += (size_t)OUTP * HID * sizeof(half_t);
  half_t* x16 = (half_t*)(ws + off); off += (size_t)BB * TT * INP * sizeof(half_t);
  float*  bsum= (float*)(ws + off);  off += (size_t)G4 * sizeof(float);
  half_t* hbuf= (half_t*)(ws + off); off += (size_t)2 * BB * HID * sizeof(half_t);
  // flag regions (zeroed together): [real 72+pad][gather 72*16][compact 72+pad][epoch fl 72 + ep 56pad]
  unsigned* fzero = (unsigned*)(ws + off);
  unsigned* flR = fzero;             // 128 dwords
  unsigned* flG = flR + 128;         // 72*16 dwords
  unsigned* flC = flG + 72 * FSTR;   // 128 dwords
  unsigned* flE = flC + 128;         // 72 dwords flags
  unsigned* epE = flE + 72;          // 56 dwords (epoch word at [0])
  const int nflags = 128 + 72 * FSTR + 128 + 128;

  hipLaunchKernelGGL(setup_kernel, dim3(512), dim3(256), 0, stream,
                     x, W_ih, W_hh, b_ih, b_hh, W_out, Wp, Wo, x16, bsum, fzero, nflags);
  hipLaunchKernelGGL(probe_gather,  dim3(NB), dim3(256), 0, stream, flG);
  hipLaunchKernelGGL(probe_compact, dim3(NB), dim3(256), 0, stream, flC);
  hipLaunchKernelGGL(probe_epoch,   dim3(NB), dim3(256), 0, stream, flE, epE);
  hipLaunchKernelGGL(lstm_persist,  dim3(NB), dim3(256), 0, stream,
                     Wp, Wo, x16, bsum, b_out, hbuf, out, flR);
}